// Round 11
// baseline (450.812 us; speedup 1.0000x reference)
//
#include <hip/hip_runtime.h>

typedef __attribute__((ext_vector_type(8))) short short8;
typedef __attribute__((ext_vector_type(4))) float floatx4;
typedef __attribute__((ext_vector_type(2))) float floatx2;
typedef unsigned short u16;
typedef unsigned int u32;

__device__ __forceinline__ float b2f(u16 s) {
  return __uint_as_float(((unsigned)s) << 16);
}
__device__ __forceinline__ u16 f2b(float f) {
  unsigned u = __float_as_uint(f);
  u = u + 0x7FFFu + ((u >> 16) & 1u);
  return (u16)(u >> 16);
}

// ---- dtype sniffer: flag=1 if raw float32, flag=0 if bf16 ----
__global__ __launch_bounds__(256) void det_k(const u16* __restrict__ x, int n, int* __restrict__ flag) {
  __shared__ int cnt;
  if (threadIdx.x == 0) cnt = 0;
  __syncthreads();
  int c = 0;
  for (int i = threadIdx.x; i < n; i += 256) {
    unsigned u = x[i];
    if ((u & 0x7F80u) == 0x7F80u) c++;
  }
  atomicAdd(&cnt, c);
  __syncthreads();
  if (threadIdx.x == 0) *flag = (cnt > 0) ? 1 : 0;
}

__device__ __forceinline__ u16 ldb16(const void* p, size_t i, int flag) {
  return flag ? f2b(((const float*)p)[i]) : ((const u16*)p)[i];
}
__device__ __forceinline__ float ldf32(const void* p, size_t i, int flag) {
  return flag ? ((const float*)p)[i] : b2f(((const u16*)p)[i]);
}

// ---------------- weight frag-reorder ----------------
struct WEnt { const void* W; u16* out; int M; int base; };
struct WPack { WEnt e[10]; int total; };

__global__ __launch_bounds__(256) void wprep_k(WPack p, const int* __restrict__ flagp) {
  int i = blockIdx.x * 256 + threadIdx.x;
  if (i >= p.total) return;
  int flag = *flagp;
  int ei = 0;
  for (int t = 1; t < 10; t++) if (i >= p.e[t].base) ei = t;
  const void* W = p.e[ei].W;
  u16* out = p.e[ei].out;
  int M = p.e[ei].M;
  int lin = i - p.e[ei].base;
  int l = lin & 63, ctks = lin >> 6;
  int NCT = M >> 4;
  int ct = ctks % NCT, ks = ctks / NCT;
  int kb = ks * 32 + ((l >> 4) << 3);
  int m = ct * 16 + (l & 15);
  short8 v;
#pragma unroll
  for (int j = 0; j < 8; j++) v[j] = (short)ldb16(W, (size_t)(kb + j) * M + m, flag);
  *(short8*)(out + (size_t)lin * 8) = v;
}

// ---------------- per-column scale/shift ----------------
struct SEnt { const void* bias; const void* g; const void* b; const void* m; const void* v; int base; };
struct SPack { SEnt e[11]; float* sc; float* sh; int total; };

__global__ __launch_bounds__(256) void sprep_k(SPack p, const int* __restrict__ flagp) {
  int i = blockIdx.x * 256 + threadIdx.x;
  if (i >= p.total) return;
  int flag = *flagp;
  int ei = 0;
  for (int t = 1; t < 11; t++) if (i >= p.e[t].base) ei = t;
  SEnt e = p.e[ei];
  int c = i - e.base;
  float bias = e.bias ? ldf32(e.bias, c, flag) : 0.f;
  float scv = 1.f, shv = bias;
  if (e.g) {
    float s = ldf32(e.g, c, flag) * rsqrtf(ldf32(e.v, c, flag) + 1e-5f);
    scv = s;
    shv = (bias - ldf32(e.m, c, flag)) * s + ldf32(e.b, c, flag);
  }
  p.sc[i] = scv;
  p.sh[i] = shv;
}

// ---------------- fused towers + dual GCN linear (wave-private LDS) ----------------
__global__ __launch_bounds__(256) void tow_k(
    const void* __restrict__ ctx, const void* __restrict__ vis,
    const u16* __restrict__ W0, const u16* __restrict__ W1,
    const u16* __restrict__ W2, const u16* __restrict__ W3,
    const u16* __restrict__ WS, const u16* __restrict__ WT,
    const float* __restrict__ sc, const float* __restrict__ sh,
    const float* __restrict__ disS, const float* __restrict__ disT,
    u16* __restrict__ hf2, u16* __restrict__ hWdS, u16* __restrict__ hWdT,
    const int* __restrict__ flagp, int N)
{
  constexpr int LA_W = 136, LB_W = 200;
  __shared__ u16 LA[4 * 16 * LA_W];
  __shared__ u16 LB[4 * 16 * LB_W];
  const int tid = threadIdx.x, w = tid >> 6, l = tid & 63;
  const int lrow = l & 15, lkb = (l >> 4) << 3;
  const int rowbase = blockIdx.x * 64 + w * 16;
  int r0 = rowbase + lrow; if (r0 >= N) r0 = N - 1;
  const int rl0 = (l >> 4) << 2;
  u16* la = LA + w * 16 * LA_W;
  u16* lb = LB + w * 16 * LB_W;
  int gflag = *flagp;

  // ---- stage A: ctx @ W0 (K=256 -> M=128), relu/bn -> la ----
  {
    floatx4 acc[8];
#pragma unroll
    for (int ct = 0; ct < 8; ct++) acc[ct] = (floatx4){0.f,0.f,0.f,0.f};
    const u16* xb = (const u16*)ctx + (size_t)r0 * 256 + lkb;
    const float* xf = (const float*)ctx + (size_t)r0 * 256 + lkb;
#pragma unroll
    for (int ks = 0; ks < 8; ks++) {
      short8 a;
      if (gflag) {
        float4 f0 = *(const float4*)(xf + ks * 32);
        float4 f1 = *(const float4*)(xf + ks * 32 + 4);
        a[0]=(short)f2b(f0.x); a[1]=(short)f2b(f0.y); a[2]=(short)f2b(f0.z); a[3]=(short)f2b(f0.w);
        a[4]=(short)f2b(f1.x); a[5]=(short)f2b(f1.y); a[6]=(short)f2b(f1.z); a[7]=(short)f2b(f1.w);
      } else {
        a = *(const short8*)(xb + ks * 32);
      }
#pragma unroll
      for (int ct = 0; ct < 8; ct++) {
        short8 b = *(const short8*)(W0 + ((size_t)(ks * 8 + ct) * 64 + l) * 8);
        acc[ct] = __builtin_amdgcn_mfma_f32_16x16x32_bf16(a, b, acc[ct], 0, 0, 0);
      }
    }
#pragma unroll
    for (int ct = 0; ct < 8; ct++) {
      int col = ct * 16 + lrow;
      float s = sc[col], t = sh[col];
#pragma unroll
      for (int r = 0; r < 4; r++)
        la[(rl0 + r) * LA_W + col] = f2b(fmaxf(acc[ct][r] * s + t, 0.f));
    }
  }
  __builtin_amdgcn_wave_barrier();

  // ---- stage B: c1 @ W1 (K=128 -> M=128) -> lb[:,0:128] ----
  {
    floatx4 acc[8];
#pragma unroll
    for (int ct = 0; ct < 8; ct++) acc[ct] = (floatx4){0.f,0.f,0.f,0.f};
#pragma unroll
    for (int ks = 0; ks < 4; ks++) {
      short8 a = *(const short8*)(la + lrow * LA_W + lkb + ks * 32);
#pragma unroll
      for (int ct = 0; ct < 8; ct++) {
        short8 b = *(const short8*)(W1 + ((size_t)(ks * 8 + ct) * 64 + l) * 8);
        acc[ct] = __builtin_amdgcn_mfma_f32_16x16x32_bf16(a, b, acc[ct], 0, 0, 0);
      }
    }
#pragma unroll
    for (int ct = 0; ct < 8; ct++) {
      int col = ct * 16 + lrow;
      float s = sc[128 + col], t = sh[128 + col];
#pragma unroll
      for (int r = 0; r < 4; r++)
        lb[(rl0 + r) * LB_W + col] = f2b(fmaxf(acc[ct][r] * s + t, 0.f));
    }
  }
  __builtin_amdgcn_wave_barrier();

  // ---- stage C: vis @ W2 (K=64 -> M=64), relu -> la[:,0:64] ----
  {
    floatx4 acc[4];
#pragma unroll
    for (int ct = 0; ct < 4; ct++) acc[ct] = (floatx4){0.f,0.f,0.f,0.f};
    const u16* xb = (const u16*)vis + (size_t)r0 * 64 + lkb;
    const float* xf = (const float*)vis + (size_t)r0 * 64 + lkb;
#pragma unroll
    for (int ks = 0; ks < 2; ks++) {
      short8 a;
      if (gflag) {
        float4 f0 = *(const float4*)(xf + ks * 32);
        float4 f1 = *(const float4*)(xf + ks * 32 + 4);
        a[0]=(short)f2b(f0.x); a[1]=(short)f2b(f0.y); a[2]=(short)f2b(f0.z); a[3]=(short)f2b(f0.w);
        a[4]=(short)f2b(f1.x); a[5]=(short)f2b(f1.y); a[6]=(short)f2b(f1.z); a[7]=(short)f2b(f1.w);
      } else {
        a = *(const short8*)(xb + ks * 32);
      }
#pragma unroll
      for (int ct = 0; ct < 4; ct++) {
        short8 b = *(const short8*)(W2 + ((size_t)(ks * 4 + ct) * 64 + l) * 8);
        acc[ct] = __builtin_amdgcn_mfma_f32_16x16x32_bf16(a, b, acc[ct], 0, 0, 0);
      }
    }
#pragma unroll
    for (int ct = 0; ct < 4; ct++) {
      int col = ct * 16 + lrow;
      float s = sc[256 + col], t = sh[256 + col];
#pragma unroll
      for (int r = 0; r < 4; r++)
        la[(rl0 + r) * LA_W + col] = f2b(fmaxf(acc[ct][r] * s + t, 0.f));
    }
  }
  __builtin_amdgcn_wave_barrier();

  // ---- stage D: t1 @ W3 (K=64 -> M=64), no relu -> lb[:,128:192] ----
  {
    floatx4 acc[4];
#pragma unroll
    for (int ct = 0; ct < 4; ct++) acc[ct] = (floatx4){0.f,0.f,0.f,0.f};
#pragma unroll
    for (int ks = 0; ks < 2; ks++) {
      short8 a = *(const short8*)(la + lrow * LA_W + lkb + ks * 32);
#pragma unroll
      for (int ct = 0; ct < 4; ct++) {
        short8 b = *(const short8*)(W3 + ((size_t)(ks * 4 + ct) * 64 + l) * 8);
        acc[ct] = __builtin_amdgcn_mfma_f32_16x16x32_bf16(a, b, acc[ct], 0, 0, 0);
      }
    }
#pragma unroll
    for (int ct = 0; ct < 4; ct++) {
      int col = ct * 16 + lrow;
      float s = sc[320 + col], t = sh[320 + col];
#pragma unroll
      for (int r = 0; r < 4; r++)
        lb[(rl0 + r) * LB_W + 128 + col] = f2b(acc[ct][r] * s + t);
    }
  }
  __builtin_amdgcn_wave_barrier();

  // ---- stage E: hf2 @ WS / WT (K=192 -> M=64 each), row-scale by dis -> la ----
  {
    floatx4 aS[4], aT[4];
#pragma unroll
    for (int ct = 0; ct < 4; ct++) { aS[ct] = (floatx4){0.f,0.f,0.f,0.f}; aT[ct] = (floatx4){0.f,0.f,0.f,0.f}; }
#pragma unroll
    for (int ks = 0; ks < 6; ks++) {
      short8 a = *(const short8*)(lb + lrow * LB_W + lkb + ks * 32);
#pragma unroll
      for (int ct = 0; ct < 4; ct++) {
        short8 bS = *(const short8*)(WS + ((size_t)(ks * 4 + ct) * 64 + l) * 8);
        short8 bT = *(const short8*)(WT + ((size_t)(ks * 4 + ct) * 64 + l) * 8);
        aS[ct] = __builtin_amdgcn_mfma_f32_16x16x32_bf16(a, bS, aS[ct], 0, 0, 0);
        aT[ct] = __builtin_amdgcn_mfma_f32_16x16x32_bf16(a, bT, aT[ct], 0, 0, 0);
      }
    }
#pragma unroll
    for (int r = 0; r < 4; r++) {
      int row = rowbase + rl0 + r;
      int rowc = row < N ? row : N - 1;
      float dS = disS[rowc], dT = disT[rowc];
#pragma unroll
      for (int ct = 0; ct < 4; ct++) {
        int col = ct * 16 + lrow;
        la[(rl0 + r) * LA_W + col] = f2b(aS[ct][r] * dS);
        la[(rl0 + r) * LA_W + 64 + col] = f2b(aT[ct][r] * dT);
      }
    }
  }
  __builtin_amdgcn_wave_barrier();

  // ---- coalesced copy-out ----
#pragma unroll
  for (int i = 0; i < 6; i++) {
    int c = i * 64 + l;
    int rl = c / 24, o = c - rl * 24;
    int row = rowbase + rl;
    if (row < N)
      *(short8*)(hf2 + (size_t)row * 192 + o * 8) = *(const short8*)(lb + rl * LB_W + o * 8);
  }
#pragma unroll
  for (int i = 0; i < 4; i++) {
    int c = i * 64 + l;
    int rl = c >> 4, o = c & 15;
    int row = rowbase + rl;
    if (row < N) {
      if (o < 8)
        *(short8*)(hWdS + (size_t)row * 64 + o * 8) = *(const short8*)(la + rl * LA_W + o * 8);
      else
        *(short8*)(hWdT + (size_t)row * 64 + (o - 8) * 8) = *(const short8*)(la + rl * LA_W + 64 + (o - 8) * 8);
    }
  }
}

// ---------------- fused fuse+head (wave-private LDS) ----------------
__global__ __launch_bounds__(256) void fhead_k(
    const u16* __restrict__ hsht,
    const u16* __restrict__ hf2,
    const u16* __restrict__ W6, const u16* __restrict__ W7,
    const u16* __restrict__ W8, const u16* __restrict__ W9,
    const float* __restrict__ sc, const float* __restrict__ sh,
    void* __restrict__ dout, const int* __restrict__ flagp, int N)
{
  constexpr int LH = 72, LZ = 136;
  __shared__ u16 ldsH[4 * 16 * LH];
  __shared__ u16 ldsZ[4 * 16 * LZ];
  const int tid = threadIdx.x, w = tid >> 6, l = tid & 63;
  const int lrow = l & 15, lkb = (l >> 4) << 3;
  const int rowbase = blockIdx.x * 64 + w * 16;
  int r0 = rowbase + lrow; if (r0 >= N) r0 = N - 1;
  const int rl0 = (l >> 4) << 2;
  int gflag = *flagp;
  u16* lh = ldsH + w * 16 * LH;
  u16* lz = ldsZ + w * 16 * LZ;
  const size_t hoff = (size_t)N * 64;

  short8 pf[6];
#pragma unroll
  for (int k = 0; k < 6; k++)
    pf[k] = *(const short8*)(hf2 + (size_t)r0 * 192 + k * 32 + lkb);

  // ---- stage 1: h = relu(hsht @ W6 + b6) ----
  {
    floatx4 acc[4];
#pragma unroll
    for (int ct = 0; ct < 4; ct++) acc[ct] = (floatx4){0.f,0.f,0.f,0.f};
#pragma unroll
    for (int ks = 0; ks < 4; ks++) {
      short8 a = *(const short8*)(hsht + (size_t)r0 * 128 + ks * 32 + lkb);
#pragma unroll
      for (int ct = 0; ct < 4; ct++) {
        short8 b = *(const short8*)(W6 + ((size_t)(ks * 4 + ct) * 64 + l) * 8);
        acc[ct] = __builtin_amdgcn_mfma_f32_16x16x32_bf16(a, b, acc[ct], 0, 0, 0);
      }
    }
#pragma unroll
    for (int ct = 0; ct < 4; ct++) {
      int col = ct * 16 + lrow;
      float s = sc[512 + col], t = sh[512 + col];
#pragma unroll
      for (int r = 0; r < 4; r++) {
        int row = rowbase + rl0 + r;
        float v = fmaxf(acc[ct][r] * s + t, 0.f);
        lh[(rl0 + r) * LH + col] = f2b(v);
        if (gflag && row < N) ((float*)dout)[hoff + (size_t)row * 64 + col] = v;
      }
    }
  }
  __builtin_amdgcn_wave_barrier();

  if (!gflag) {
#pragma unroll
    for (int i = 0; i < 2; i++) {
      int c = i * 64 + l;
      int rl = c >> 3, o = c & 7;
      int row = rowbase + rl;
      if (row < N)
        *(short8*)((u16*)dout + hoff + (size_t)row * 64 + o * 8) = *(const short8*)(lh + rl * LH + o * 8);
    }
  }

  // ---- stage 2: z1 = relu(bn3([h | hf2] @ W7 + b7)) ----
  {
    floatx4 acc[8];
#pragma unroll
    for (int ct = 0; ct < 8; ct++) acc[ct] = (floatx4){0.f,0.f,0.f,0.f};
#pragma unroll
    for (int ks = 0; ks < 8; ks++) {
      short8 a;
      if (ks < 2) a = *(const short8*)(lh + lrow * LH + lkb + ks * 32);
      else        a = pf[ks - 2];
#pragma unroll
      for (int ct = 0; ct < 8; ct++) {
        short8 b = *(const short8*)(W7 + ((size_t)(ks * 8 + ct) * 64 + l) * 8);
        acc[ct] = __builtin_amdgcn_mfma_f32_16x16x32_bf16(a, b, acc[ct], 0, 0, 0);
      }
    }
#pragma unroll
    for (int ct = 0; ct < 8; ct++) {
      int col = ct * 16 + lrow;
      float s = sc[576 + col], t = sh[576 + col];
#pragma unroll
      for (int r = 0; r < 4; r++)
        lz[(rl0 + r) * LZ + col] = f2b(fmaxf(acc[ct][r] * s + t, 0.f));
    }
  }
  __builtin_amdgcn_wave_barrier();

  // ---- stage 3: z2 = relu(z1 @ W8 + b8) -> lh ----
  {
    floatx4 acc[4];
#pragma unroll
    for (int ct = 0; ct < 4; ct++) acc[ct] = (floatx4){0.f,0.f,0.f,0.f};
#pragma unroll
    for (int ks = 0; ks < 4; ks++) {
      short8 a = *(const short8*)(lz + lrow * LZ + lkb + ks * 32);
#pragma unroll
      for (int ct = 0; ct < 4; ct++) {
        short8 b = *(const short8*)(W8 + ((size_t)(ks * 4 + ct) * 64 + l) * 8);
        acc[ct] = __builtin_amdgcn_mfma_f32_16x16x32_bf16(a, b, acc[ct], 0, 0, 0);
      }
    }
#pragma unroll
    for (int ct = 0; ct < 4; ct++) {
      int col = ct * 16 + lrow;
      float s = sc[704 + col], t = sh[704 + col];
#pragma unroll
      for (int r = 0; r < 4; r++)
        lh[(rl0 + r) * LH + col] = f2b(fmaxf(acc[ct][r] * s + t, 0.f));
    }
  }
  __builtin_amdgcn_wave_barrier();

  // ---- stage 4: out = z2 @ W9 + b9 ----
  {
    floatx4 acc[4];
#pragma unroll
    for (int ct = 0; ct < 4; ct++) acc[ct] = (floatx4){0.f,0.f,0.f,0.f};
#pragma unroll
    for (int ks = 0; ks < 2; ks++) {
      short8 a = *(const short8*)(lh + lrow * LH + lkb + ks * 32);
#pragma unroll
      for (int ct = 0; ct < 4; ct++) {
        short8 b = *(const short8*)(W9 + ((size_t)(ks * 4 + ct) * 64 + l) * 8);
        acc[ct] = __builtin_amdgcn_mfma_f32_16x16x32_bf16(a, b, acc[ct], 0, 0, 0);
      }
    }
#pragma unroll
    for (int ct = 0; ct < 4; ct++) {
      int col = ct * 16 + lrow;
      float s = sc[768 + col], t = sh[768 + col];
#pragma unroll
      for (int r = 0; r < 4; r++) {
        int row = rowbase + rl0 + r;
        float v = acc[ct][r] * s + t;
        if (gflag) { if (row < N) ((float*)dout)[(size_t)row * 64 + col] = v; }
        else lz[(rl0 + r) * LZ + col] = f2b(v);
      }
    }
  }
  __builtin_amdgcn_wave_barrier();
  if (!gflag) {
#pragma unroll
    for (int i = 0; i < 2; i++) {
      int c = i * 64 + l;
      int rl = c >> 3, o = c & 7;
      int row = rowbase + rl;
      if (row < N)
        *(short8*)((u16*)dout + (size_t)row * 64 + o * 8) = *(const short8*)(lz + rl * LZ + o * 8);
    }
  }
}

// ---------------- chunked bucket histogram (both graphs), slice = chunk&63 ----------------
#define CH 8192
__global__ __launch_bounds__(512) void histc_k(const int* __restrict__ dS, const int* __restrict__ dT,
                                               u32* __restrict__ hslS, u32* __restrict__ hslT, int E) {
  __shared__ u32 h[2048];
  int t = threadIdx.x;
  for (int i = t; i < 2048; i += 512) h[i] = 0;
  __syncthreads();
  int c0 = blockIdx.x * CH;
  int cend = c0 + CH; if (cend > E) cend = E;
  for (int i = c0 + t; i < cend; i += 512) {
    atomicAdd(&h[dS[i] >> 7], 1u);
    atomicAdd(&h[1024 + (dT[i] >> 7)], 1u);
  }
  __syncthreads();
  int slice = blockIdx.x & 63;
  for (int b = t; b < 1024; b += 512) {
    u32 a = h[b], bt = h[1024 + b];
    if (a)  atomicAdd(&hslS[b * 64 + slice], a);
    if (bt) atomicAdd(&hslT[b * 64 + slice], bt);
  }
}

// ---------------- scan chain (131072 elements, both graphs) ----------------
__global__ __launch_bounds__(256) void scan1_k(const u32* __restrict__ cnt, int* __restrict__ rowp,
                                               u32* __restrict__ bsum, int N) {
  __shared__ u32 sm[256];
  int t = threadIdx.x;
  int base = blockIdx.x * 1024 + t * 4;
  u32 v0 = 0, v1 = 0, v2 = 0, v3 = 0;
  if (base + 3 < N) {
    uint4 u = *(const uint4*)(cnt + base);
    v0 = u.x; v1 = u.y; v2 = u.z; v3 = u.w;
  } else {
    if (base + 0 < N) v0 = cnt[base + 0];
    if (base + 1 < N) v1 = cnt[base + 1];
    if (base + 2 < N) v2 = cnt[base + 2];
  }
  u32 tsum = v0 + v1 + v2 + v3;
  u32 x = tsum;
  sm[t] = x;
  for (int o = 1; o < 256; o <<= 1) {
    __syncthreads();
    u32 y = (t >= o) ? sm[t - o] : 0u;
    __syncthreads();
    x += y;
    sm[t] = x;
  }
  u32 ex = x - tsum;
  if (base + 0 < N) rowp[base + 0] = (int)ex;
  if (base + 1 < N) rowp[base + 1] = (int)(ex + v0);
  if (base + 2 < N) rowp[base + 2] = (int)(ex + v0 + v1);
  if (base + 3 < N) rowp[base + 3] = (int)(ex + v0 + v1 + v2);
  if (t == 255) bsum[blockIdx.x] = x;
}

__global__ __launch_bounds__(256) void scan2_k(u32* __restrict__ bsum, int nb, int* __restrict__ rowp, int N) {
  __shared__ u32 sm[256];
  int t = threadIdx.x;
  u32 v = (t < nb) ? bsum[t] : 0u;
  u32 x = v;
  sm[t] = x;
  for (int o = 1; o < 256; o <<= 1) {
    __syncthreads();
    u32 y = (t >= o) ? sm[t - o] : 0u;
    __syncthreads();
    x += y;
    sm[t] = x;
  }
  if (t < nb) bsum[t] = x - v;
  if (t == 255) rowp[N] = (int)x;
}

__global__ __launch_bounds__(256) void scan3_k(int* __restrict__ rowp, const u32* __restrict__ bsum, int N) {
  int t = threadIdx.x, base = blockIdx.x * 1024 + t * 4;
  u32 add = bsum[blockIdx.x];
#pragma unroll
  for (int j = 0; j < 4; j++) {
    int i = base + j;
    if (i < N) rowp[i] += (int)add;
  }
}

// ---------------- bucket bases ----------------
__global__ __launch_bounds__(256) void bbx_k(const int* __restrict__ oft, int* __restrict__ bb, int nbb) {
  int i = blockIdx.x * 256 + threadIdx.x;
  if (i <= nbb) bb[i] = oft[i * 64];
}

// ---------------- LDS-staged partition (both graphs in one dispatch) ----------------
__global__ __launch_bounds__(512) void part2_k(const int* __restrict__ spe, const int* __restrict__ tre,
                                               u32* __restrict__ cur0, u32* __restrict__ pairs,
                                               int E, int NC) {
  __shared__ u32 cntA[1024];
  __shared__ u32 offA[1024];
  __shared__ u32 stage[CH];
  __shared__ u32 stot;
  int t = threadIdx.x;
  int gb = blockIdx.x;
  bool gT = gb >= NC;
  int cb = gT ? gb - NC : gb;
  const int* src = gT ? tre : spe;
  const int* dst = src + E;
  u32* cur = cur0 + (gT ? 65536 : 0);
  cntA[t * 2] = 0; cntA[t * 2 + 1] = 0;
  __syncthreads();
  int c0 = cb * CH;
  int cend = c0 + CH; if (cend > E) cend = E;
  for (int i = c0 + t; i < cend; i += 512)
    atomicAdd(&cntA[dst[i] >> 7], 1u);
  __syncthreads();
  u32 v0 = cntA[t * 2], v1 = cntA[t * 2 + 1];
  u32 ts = v0 + v1, x = ts;
  stage[t] = x;
  for (int o = 1; o < 512; o <<= 1) {
    __syncthreads();
    u32 y = (t >= o) ? stage[t - o] : 0u;
    __syncthreads();
    x += y;
    stage[t] = x;
  }
  u32 ex = x - ts;
  __syncthreads();
  offA[t * 2] = ex;
  offA[t * 2 + 1] = ex + v0;
  cntA[t * 2] = ex;
  cntA[t * 2 + 1] = ex + v0;
  if (t == 511) stot = x;
  __syncthreads();
  for (int i = c0 + t; i < cend; i += 512) {
    int d = dst[i];
    u32 pos = atomicAdd(&cntA[d >> 7], 1u);
    stage[pos] = ((u32)(d & 127) << 20) | (u32)src[i];
  }
  __syncthreads();
  int slice = cb & 63;
  for (int bk = t; bk < 1024; bk += 512) {
    u32 beg = offA[bk];
    u32 fin = (bk == 1023) ? stot : offA[bk + 1];
    u32 n = fin - beg;
    if (n) {
      u32 g = atomicAdd(&cur[(u32)bk * 64 + slice], n);
      for (u32 j = 0; j < n; j++) pairs[g + j] = stage[beg + j];
    }
  }
}

// ---------------- per-bucket counting sort (in place) + dis + rowp ----------------
// Stages bucket in LDS, counts, parallel-scans, writes dis/rowp, scatters sorted
// src-ids back over pairs[] (bucket-local region).
#define SMX 5120
__global__ __launch_bounds__(512) void sortdis_k(u32* __restrict__ pairs, const int* __restrict__ bb,
                                                 float* __restrict__ disS, float* __restrict__ disT,
                                                 int* __restrict__ rowpS, int* __restrict__ rowpT,
                                                 int nb, int N) {
  __shared__ u32 scnt[128];
  __shared__ u32 ssc[128];
  __shared__ u32 scur[128];
  __shared__ u32 stage[SMX];
  int b = blockIdx.x, t = threadIdx.x;
  bool gT = b >= nb;
  int j = gT ? b - nb : b;
  int bbi = (gT ? 1024 : 0) + j;
  float* dis = gT ? disT : disS;
  int* rowp = gT ? rowpT : rowpS;
  if (t < 128) scnt[t] = 0;
  __syncthreads();
  int base = bb[bbi], end = bb[bbi + 1];
  int size = end - base;
  if (size > SMX) size = SMX;
  for (int i = t; i < size; i += 512) {
    u32 p = pairs[base + i];
    stage[i] = p;
    atomicAdd(&scnt[(p >> 20) & 127], 1u);
  }
  __syncthreads();
  // parallel inclusive scan over 128 counters (Hillis-Steele)
  if (t < 128) ssc[t] = scnt[t];
  __syncthreads();
  for (int o = 1; o < 128; o <<= 1) {
    u32 y = 0;
    if (t < 128 && t >= o) y = ssc[t - o];
    __syncthreads();
    if (t < 128) ssc[t] += y;
    __syncthreads();
  }
  if (t < 128) {
    u32 ex = ssc[t] - scnt[t];
    scur[t] = ex;
    int n = j * 128 + t;
    if (n < N) {
      dis[n] = rsqrtf((float)scnt[t] + 1.f);
      rowp[n] = base + (int)ex;
    }
  }
  if (t == 0) {
    int idx = j * 128 + 128;
    if (idx > N) idx = N;
    rowp[idx] = base + size;
  }
  __syncthreads();
  for (int i = t; i < size; i += 512) {
    u32 p = stage[i];
    u32 nl = (p >> 20) & 127;
    u32 pos = atomicAdd(&scur[nl], 1u);
    pairs[base + (int)pos] = p & 0xFFFFFu;
  }
}

// ---------------- pure gather SpMM (zero LDS, both graphs) ----------------
// eg = lane>>3 (edge slot), fo = (lane&7)*8 (feature octet).
__device__ __forceinline__ void acc8(floatx2* a2, short8 v) {
  const u32* wv = (const u32*)&v;
#pragma unroll
  for (int p = 0; p < 4; p++) {
    u32 w = wv[p];
    floatx2 e;
    e.x = __uint_as_float(w << 16);
    e.y = __uint_as_float(w & 0xFFFF0000u);
    a2[p] += e;
  }
}

__global__ __launch_bounds__(512) void spmm_k(const u32* __restrict__ csr,
                                              const int* __restrict__ rowpS, const int* __restrict__ rowpT,
                                              const u16* __restrict__ hWdS, const u16* __restrict__ hWdT,
                                              const float* __restrict__ biasS, const float* __restrict__ biasT,
                                              u16* __restrict__ hsht, int nb, int N) {
  int b = blockIdx.x, t = threadIdx.x;
  bool gT = b >= nb;
  int j = gT ? b - nb : b;
  const int* rowp = gT ? rowpT : rowpS;
  const u16* hWd = gT ? hWdT : hWdS;
  const float* biasf = gT ? biasT : biasS;
  int goff = gT ? 64 : 0;

  const int wid = t >> 6, lane = t & 63;
  const int eg = lane >> 3;
  const int fo = (lane & 7) * 8;
  const u16* hp = hWd + fo;
  floatx2 bi2[4];
#pragma unroll
  for (int p = 0; p < 4; p++) bi2[p] = *(const floatx2*)(biasf + fo + 2 * p);

#pragma unroll 1
  for (int k = 0; k < 16; k++) {
    int nl = wid + (k << 3);
    int n = j * 128 + nl;
    if (n >= N) continue;
    int off = rowp[n], end = rowp[n + 1];
    int cnt = end - off;
    floatx2 a2[4];
#pragma unroll
    for (int p = 0; p < 4; p++) a2[p] = (floatx2){0.f, 0.f};
    int i = 0;
    for (; i + 16 <= cnt; i += 16) {
      u32 s0 = csr[off + i + eg];
      u32 s1 = csr[off + i + 8 + eg];
      short8 v0 = *(const short8*)(hp + (size_t)s0 * 64);
      short8 v1 = *(const short8*)(hp + (size_t)s1 * 64);
      acc8(a2, v0);
      acc8(a2, v1);
    }
    if (i + 8 <= cnt) {
      u32 s0 = csr[off + i + eg];
      acc8(a2, *(const short8*)(hp + (size_t)s0 * 64));
      i += 8;
    }
    int rem = cnt - i;
    if (eg < rem) {
      u32 s0 = csr[off + i + eg];
      acc8(a2, *(const short8*)(hp + (size_t)s0 * 64));
    }
#pragma unroll
    for (int m = 8; m <= 32; m <<= 1) {
#pragma unroll
      for (int p = 0; p < 4; p++) {
        floatx2 o;
        o.x = __shfl_xor(a2[p].x, m, 64);
        o.y = __shfl_xor(a2[p].y, m, 64);
        a2[p] += o;
      }
    }
    float disn = rsqrtf((float)cnt + 1.f);
    short8 sv = *(const short8*)(hp + (size_t)n * 64);
    const u32* swv = (const u32*)&sv;
    short8 o;
    u32* ow = (u32*)&o;
#pragma unroll
    for (int p = 0; p < 4; p++) {
      u32 w = swv[p];
      float lo = disn * (a2[p].x + __uint_as_float(w << 16)) + bi2[p].x;
      float hi = disn * (a2[p].y + __uint_as_float(w & 0xFFFF0000u)) + bi2[p].y;
      lo = fmaxf(lo, 0.f);
      hi = fmaxf(hi, 0.f);
      ow[p] = ((u32)f2b(hi) << 16) | (u32)f2b(lo);
    }
    if (eg == 0)
      *(short8*)(hsht + (size_t)n * 128 + goff + fo) = o;
  }
}

extern "C" void kernel_launch(void* const* d_in, const int* in_sizes, int n_in,
                              void* d_out, int out_size, void* d_ws, size_t ws_size,
                              hipStream_t stream) {
  const int N = in_sizes[0] / 256;
  const int E = in_sizes[2] / 2;
  const int nb = (N + 127) >> 7;
  const int NC = (E + CH - 1) / CH;
  const void* ctx = d_in[0];
  const void* vis = d_in[1];
  const int* spe = (const int*)d_in[2];
  const int* tre = (const int*)d_in[3];
  (void)n_in; (void)out_size; (void)ws_size;

  char* ws = (char*)d_ws;
  size_t off = 0;
  auto alloc = [&](size_t b) { size_t r = off; off += (b + 255) & ~(size_t)255; return r; };
  const size_t o_hsl  = alloc(2 * 65536 * 4);
  const size_t o_oft  = alloc(131080 * 4);
  const size_t o_bb   = alloc(2056 * 4);
  const size_t o_bsum = alloc(256 * 4);
  const size_t o_disS = alloc((size_t)N * 4);
  const size_t o_disT = alloc((size_t)N * 4);
  const size_t o_rwS  = alloc((size_t)(N + 16) * 4);
  const size_t o_rwT  = alloc((size_t)(N + 16) * 4);
  const size_t o_pr   = alloc((size_t)2 * E * 4);
  const size_t o_hf2  = alloc((size_t)N * 192 * 2);
  const size_t o_hsht = alloc((size_t)N * 128 * 2);
  const size_t o_hWdS = alloc((size_t)N * 64 * 2);
  const size_t o_hWdT = alloc((size_t)N * 64 * 2);
  const size_t o_wf   = alloc((size_t)135168 * 2);
  const size_t o_sc   = alloc((size_t)896 * 4);
  const size_t o_sh   = alloc((size_t)896 * 4);
  const size_t o_fl   = alloc(256);

  u32* hsl  = (u32*)(ws + o_hsl);
  int* oft  = (int*)(ws + o_oft);
  int* bb   = (int*)(ws + o_bb);
  u32* bsum = (u32*)(ws + o_bsum);
  float* disS = (float*)(ws + o_disS);
  float* disT = (float*)(ws + o_disT);
  int* rowpS = (int*)(ws + o_rwS);
  int* rowpT = (int*)(ws + o_rwT);
  u32* pairs = (u32*)(ws + o_pr);
  u16* hf2   = (u16*)(ws + o_hf2);
  u16* hsht  = (u16*)(ws + o_hsht);
  u16* hWdS  = (u16*)(ws + o_hWdS);
  u16* hWdT  = (u16*)(ws + o_hWdT);
  u16* wf    = (u16*)(ws + o_wf);
  float* sc  = (float*)(ws + o_sc);
  float* sh  = (float*)(ws + o_sh);
  int* flagp = (int*)(ws + o_fl);

  det_k<<<1, 256, 0, stream>>>((const u16*)ctx, 4096, flagp);
  hipMemsetAsync(ws + o_hsl, 0, 2 * 65536 * 4, stream);

  // ---- weight frag prep ----
  const int wfoff[10] = {0, 32768, 49152, 53248, 57344, 69632, 81920, 90112, 122880, 131072};
  const int wbase[10] = {0, 4096, 6144, 6656, 7168, 8704, 10240, 11264, 15360, 16384};
  const int wM[10]    = {128, 128, 64, 64, 64, 64, 64, 128, 64, 64};
  const int widx[10]  = {4, 10, 16, 18, 20, 22, 24, 26, 32, 34};
  WPack wp;
  for (int i = 0; i < 10; i++) wp.e[i] = {d_in[widx[i]], wf + (size_t)wfoff[i], wM[i], wbase[i]};
  wp.total = 16896;
  wprep_k<<<(wp.total + 255) / 256, 256, 0, stream>>>(wp, flagp);

  // ---- scale/shift prep ----
  const int sbase[11] = {0, 128, 256, 320, 384, 448, 512, 576, 704, 768, 832};
  const int bidx[11] = {5, 11, 17, 19, 21, 23, 25, 27, 33, 35, -1};
  const int gidx[11] = {6, 12, -1, -1, -1, -1, -1, 28, -1, -1, -1};
  SPack spk;
  for (int i = 0; i < 11; i++) {
    const void* bias = bidx[i] >= 0 ? d_in[bidx[i]] : nullptr;
    const void* g = gidx[i] >= 0 ? d_in[gidx[i]] : nullptr;
    const void* b = gidx[i] >= 0 ? d_in[gidx[i] + 1] : nullptr;
    const void* m = gidx[i] >= 0 ? d_in[gidx[i] + 2] : nullptr;
    const void* v = gidx[i] >= 0 ? d_in[gidx[i] + 3] : nullptr;
    spk.e[i] = {bias, g, b, m, v, sbase[i]};
  }
  spk.sc = sc; spk.sh = sh; spk.total = 896;
  sprep_k<<<4, 256, 0, stream>>>(spk, flagp);

  // ---- graph prep ----
  histc_k<<<NC, 512, 0, stream>>>(spe + E, tre + E, hsl, hsl + 65536, E);
  scan1_k<<<128, 256, 0, stream>>>(hsl, oft, bsum, 131072);
  scan2_k<<<1, 256, 0, stream>>>(bsum, 128, oft, 131072);
  scan3_k<<<128, 256, 0, stream>>>(oft, bsum, 131072);
  bbx_k<<<9, 256, 0, stream>>>(oft, bb, 2048);
  part2_k<<<2 * NC, 512, 0, stream>>>(spe, tre, (u32*)oft, pairs, E, NC);
  sortdis_k<<<2 * nb, 512, 0, stream>>>(pairs, bb, disS, disT, rowpS, rowpT, nb, N);

  const int G64 = (N + 63) / 64;
  tow_k<<<G64, 256, 0, stream>>>(ctx, vis,
      wf + wfoff[0], wf + wfoff[1], wf + wfoff[2], wf + wfoff[3],
      wf + wfoff[4], wf + wfoff[5],
      sc, sh, disS, disT, hf2, hWdS, hWdT, flagp, N);
  spmm_k<<<2 * nb, 512, 0, stream>>>(pairs, rowpS, rowpT, hWdS, hWdT, sh + 384, sh + 448, hsht, nb, N);
  fhead_k<<<G64, 256, 0, stream>>>(hsht, hf2,
      wf + wfoff[6], wf + wfoff[7], wf + wfoff[8], wf + wfoff[9],
      sc, sh, d_out, flagp, N);
}

// Round 12
// 397.397 us; speedup vs baseline: 1.1344x; 1.1344x over previous
//
#include <hip/hip_runtime.h>

typedef __attribute__((ext_vector_type(8))) short short8;
typedef __attribute__((ext_vector_type(4))) float floatx4;
typedef __attribute__((ext_vector_type(2))) float floatx2;
typedef unsigned short u16;
typedef unsigned int u32;

__device__ __forceinline__ float b2f(u16 s) {
  return __uint_as_float(((unsigned)s) << 16);
}
__device__ __forceinline__ u16 f2b(float f) {
  unsigned u = __float_as_uint(f);
  u = u + 0x7FFFu + ((u >> 16) & 1u);
  return (u16)(u >> 16);
}

// ---- dtype sniffer: flag=1 if raw float32, flag=0 if bf16 ----
__global__ __launch_bounds__(256) void det_k(const u16* __restrict__ x, int n, int* __restrict__ flag) {
  __shared__ int cnt;
  if (threadIdx.x == 0) cnt = 0;
  __syncthreads();
  int c = 0;
  for (int i = threadIdx.x; i < n; i += 256) {
    unsigned u = x[i];
    if ((u & 0x7F80u) == 0x7F80u) c++;
  }
  atomicAdd(&cnt, c);
  __syncthreads();
  if (threadIdx.x == 0) *flag = (cnt > 0) ? 1 : 0;
}

__device__ __forceinline__ u16 ldb16(const void* p, size_t i, int flag) {
  return flag ? f2b(((const float*)p)[i]) : ((const u16*)p)[i];
}
__device__ __forceinline__ float ldf32(const void* p, size_t i, int flag) {
  return flag ? ((const float*)p)[i] : b2f(((const u16*)p)[i]);
}

// ---------------- weight frag-reorder ----------------
struct WEnt { const void* W; u16* out; int M; int base; };
struct WPack { WEnt e[10]; int total; };

__global__ __launch_bounds__(256) void wprep_k(WPack p, const int* __restrict__ flagp) {
  int i = blockIdx.x * 256 + threadIdx.x;
  if (i >= p.total) return;
  int flag = *flagp;
  int ei = 0;
  for (int t = 1; t < 10; t++) if (i >= p.e[t].base) ei = t;
  const void* W = p.e[ei].W;
  u16* out = p.e[ei].out;
  int M = p.e[ei].M;
  int lin = i - p.e[ei].base;
  int l = lin & 63, ctks = lin >> 6;
  int NCT = M >> 4;
  int ct = ctks % NCT, ks = ctks / NCT;
  int kb = ks * 32 + ((l >> 4) << 3);
  int m = ct * 16 + (l & 15);
  short8 v;
#pragma unroll
  for (int j = 0; j < 8; j++) v[j] = (short)ldb16(W, (size_t)(kb + j) * M + m, flag);
  *(short8*)(out + (size_t)lin * 8) = v;
}

// ---------------- per-column scale/shift ----------------
struct SEnt { const void* bias; const void* g; const void* b; const void* m; const void* v; int base; };
struct SPack { SEnt e[11]; float* sc; float* sh; int total; };

__global__ __launch_bounds__(256) void sprep_k(SPack p, const int* __restrict__ flagp) {
  int i = blockIdx.x * 256 + threadIdx.x;
  if (i >= p.total) return;
  int flag = *flagp;
  int ei = 0;
  for (int t = 1; t < 11; t++) if (i >= p.e[t].base) ei = t;
  SEnt e = p.e[ei];
  int c = i - e.base;
  float bias = e.bias ? ldf32(e.bias, c, flag) : 0.f;
  float scv = 1.f, shv = bias;
  if (e.g) {
    float s = ldf32(e.g, c, flag) * rsqrtf(ldf32(e.v, c, flag) + 1e-5f);
    scv = s;
    shv = (bias - ldf32(e.m, c, flag)) * s + ldf32(e.b, c, flag);
  }
  p.sc[i] = scv;
  p.sh[i] = shv;
}

// ---------------- fused towers + dual GCN linear (wave-private LDS) ----------------
__global__ __launch_bounds__(256) void tow_k(
    const void* __restrict__ ctx, const void* __restrict__ vis,
    const u16* __restrict__ W0, const u16* __restrict__ W1,
    const u16* __restrict__ W2, const u16* __restrict__ W3,
    const u16* __restrict__ WS, const u16* __restrict__ WT,
    const float* __restrict__ sc, const float* __restrict__ sh,
    const float* __restrict__ disS, const float* __restrict__ disT,
    u16* __restrict__ hf2, u16* __restrict__ hWdS, u16* __restrict__ hWdT,
    const int* __restrict__ flagp, int N)
{
  constexpr int LA_W = 136, LB_W = 200;
  __shared__ u16 LA[4 * 16 * LA_W];
  __shared__ u16 LB[4 * 16 * LB_W];
  const int tid = threadIdx.x, w = tid >> 6, l = tid & 63;
  const int lrow = l & 15, lkb = (l >> 4) << 3;
  const int rowbase = blockIdx.x * 64 + w * 16;
  int r0 = rowbase + lrow; if (r0 >= N) r0 = N - 1;
  const int rl0 = (l >> 4) << 2;
  u16* la = LA + w * 16 * LA_W;
  u16* lb = LB + w * 16 * LB_W;
  int gflag = *flagp;

  // ---- stage A: ctx @ W0 (K=256 -> M=128), relu/bn -> la ----
  {
    floatx4 acc[8];
#pragma unroll
    for (int ct = 0; ct < 8; ct++) acc[ct] = (floatx4){0.f,0.f,0.f,0.f};
    const u16* xb = (const u16*)ctx + (size_t)r0 * 256 + lkb;
    const float* xf = (const float*)ctx + (size_t)r0 * 256 + lkb;
#pragma unroll
    for (int ks = 0; ks < 8; ks++) {
      short8 a;
      if (gflag) {
        float4 f0 = *(const float4*)(xf + ks * 32);
        float4 f1 = *(const float4*)(xf + ks * 32 + 4);
        a[0]=(short)f2b(f0.x); a[1]=(short)f2b(f0.y); a[2]=(short)f2b(f0.z); a[3]=(short)f2b(f0.w);
        a[4]=(short)f2b(f1.x); a[5]=(short)f2b(f1.y); a[6]=(short)f2b(f1.z); a[7]=(short)f2b(f1.w);
      } else {
        a = *(const short8*)(xb + ks * 32);
      }
#pragma unroll
      for (int ct = 0; ct < 8; ct++) {
        short8 b = *(const short8*)(W0 + ((size_t)(ks * 8 + ct) * 64 + l) * 8);
        acc[ct] = __builtin_amdgcn_mfma_f32_16x16x32_bf16(a, b, acc[ct], 0, 0, 0);
      }
    }
#pragma unroll
    for (int ct = 0; ct < 8; ct++) {
      int col = ct * 16 + lrow;
      float s = sc[col], t = sh[col];
#pragma unroll
      for (int r = 0; r < 4; r++)
        la[(rl0 + r) * LA_W + col] = f2b(fmaxf(acc[ct][r] * s + t, 0.f));
    }
  }
  __builtin_amdgcn_wave_barrier();

  // ---- stage B: c1 @ W1 (K=128 -> M=128) -> lb[:,0:128] ----
  {
    floatx4 acc[8];
#pragma unroll
    for (int ct = 0; ct < 8; ct++) acc[ct] = (floatx4){0.f,0.f,0.f,0.f};
#pragma unroll
    for (int ks = 0; ks < 4; ks++) {
      short8 a = *(const short8*)(la + lrow * LA_W + lkb + ks * 32);
#pragma unroll
      for (int ct = 0; ct < 8; ct++) {
        short8 b = *(const short8*)(W1 + ((size_t)(ks * 8 + ct) * 64 + l) * 8);
        acc[ct] = __builtin_amdgcn_mfma_f32_16x16x32_bf16(a, b, acc[ct], 0, 0, 0);
      }
    }
#pragma unroll
    for (int ct = 0; ct < 8; ct++) {
      int col = ct * 16 + lrow;
      float s = sc[128 + col], t = sh[128 + col];
#pragma unroll
      for (int r = 0; r < 4; r++)
        lb[(rl0 + r) * LB_W + col] = f2b(fmaxf(acc[ct][r] * s + t, 0.f));
    }
  }
  __builtin_amdgcn_wave_barrier();

  // ---- stage C: vis @ W2 (K=64 -> M=64), relu -> la[:,0:64] ----
  {
    floatx4 acc[4];
#pragma unroll
    for (int ct = 0; ct < 4; ct++) acc[ct] = (floatx4){0.f,0.f,0.f,0.f};
    const u16* xb = (const u16*)vis + (size_t)r0 * 64 + lkb;
    const float* xf = (const float*)vis + (size_t)r0 * 64 + lkb;
#pragma unroll
    for (int ks = 0; ks < 2; ks++) {
      short8 a;
      if (gflag) {
        float4 f0 = *(const float4*)(xf + ks * 32);
        float4 f1 = *(const float4*)(xf + ks * 32 + 4);
        a[0]=(short)f2b(f0.x); a[1]=(short)f2b(f0.y); a[2]=(short)f2b(f0.z); a[3]=(short)f2b(f0.w);
        a[4]=(short)f2b(f1.x); a[5]=(short)f2b(f1.y); a[6]=(short)f2b(f1.z); a[7]=(short)f2b(f1.w);
      } else {
        a = *(const short8*)(xb + ks * 32);
      }
#pragma unroll
      for (int ct = 0; ct < 4; ct++) {
        short8 b = *(const short8*)(W2 + ((size_t)(ks * 4 + ct) * 64 + l) * 8);
        acc[ct] = __builtin_amdgcn_mfma_f32_16x16x32_bf16(a, b, acc[ct], 0, 0, 0);
      }
    }
#pragma unroll
    for (int ct = 0; ct < 4; ct++) {
      int col = ct * 16 + lrow;
      float s = sc[256 + col], t = sh[256 + col];
#pragma unroll
      for (int r = 0; r < 4; r++)
        la[(rl0 + r) * LA_W + col] = f2b(fmaxf(acc[ct][r] * s + t, 0.f));
    }
  }
  __builtin_amdgcn_wave_barrier();

  // ---- stage D: t1 @ W3 (K=64 -> M=64), no relu -> lb[:,128:192] ----
  {
    floatx4 acc[4];
#pragma unroll
    for (int ct = 0; ct < 4; ct++) acc[ct] = (floatx4){0.f,0.f,0.f,0.f};
#pragma unroll
    for (int ks = 0; ks < 2; ks++) {
      short8 a = *(const short8*)(la + lrow * LA_W + lkb + ks * 32);
#pragma unroll
      for (int ct = 0; ct < 4; ct++) {
        short8 b = *(const short8*)(W3 + ((size_t)(ks * 4 + ct) * 64 + l) * 8);
        acc[ct] = __builtin_amdgcn_mfma_f32_16x16x32_bf16(a, b, acc[ct], 0, 0, 0);
      }
    }
#pragma unroll
    for (int ct = 0; ct < 4; ct++) {
      int col = ct * 16 + lrow;
      float s = sc[320 + col], t = sh[320 + col];
#pragma unroll
      for (int r = 0; r < 4; r++)
        lb[(rl0 + r) * LB_W + 128 + col] = f2b(acc[ct][r] * s + t);
    }
  }
  __builtin_amdgcn_wave_barrier();

  // ---- stage E: hf2 @ WS / WT (K=192 -> M=64 each), row-scale by dis -> la ----
  {
    floatx4 aS[4], aT[4];
#pragma unroll
    for (int ct = 0; ct < 4; ct++) { aS[ct] = (floatx4){0.f,0.f,0.f,0.f}; aT[ct] = (floatx4){0.f,0.f,0.f,0.f}; }
#pragma unroll
    for (int ks = 0; ks < 6; ks++) {
      short8 a = *(const short8*)(lb + lrow * LB_W + lkb + ks * 32);
#pragma unroll
      for (int ct = 0; ct < 4; ct++) {
        short8 bS = *(const short8*)(WS + ((size_t)(ks * 4 + ct) * 64 + l) * 8);
        short8 bT = *(const short8*)(WT + ((size_t)(ks * 4 + ct) * 64 + l) * 8);
        aS[ct] = __builtin_amdgcn_mfma_f32_16x16x32_bf16(a, bS, aS[ct], 0, 0, 0);
        aT[ct] = __builtin_amdgcn_mfma_f32_16x16x32_bf16(a, bT, aT[ct], 0, 0, 0);
      }
    }
#pragma unroll
    for (int r = 0; r < 4; r++) {
      int row = rowbase + rl0 + r;
      int rowc = row < N ? row : N - 1;
      float dS = disS[rowc], dT = disT[rowc];
#pragma unroll
      for (int ct = 0; ct < 4; ct++) {
        int col = ct * 16 + lrow;
        la[(rl0 + r) * LA_W + col] = f2b(aS[ct][r] * dS);
        la[(rl0 + r) * LA_W + 64 + col] = f2b(aT[ct][r] * dT);
      }
    }
  }
  __builtin_amdgcn_wave_barrier();

  // ---- coalesced copy-out ----
#pragma unroll
  for (int i = 0; i < 6; i++) {
    int c = i * 64 + l;
    int rl = c / 24, o = c - rl * 24;
    int row = rowbase + rl;
    if (row < N)
      *(short8*)(hf2 + (size_t)row * 192 + o * 8) = *(const short8*)(lb + rl * LB_W + o * 8);
  }
#pragma unroll
  for (int i = 0; i < 4; i++) {
    int c = i * 64 + l;
    int rl = c >> 4, o = c & 15;
    int row = rowbase + rl;
    if (row < N) {
      if (o < 8)
        *(short8*)(hWdS + (size_t)row * 64 + o * 8) = *(const short8*)(la + rl * LA_W + o * 8);
      else
        *(short8*)(hWdT + (size_t)row * 64 + (o - 8) * 8) = *(const short8*)(la + rl * LA_W + 64 + (o - 8) * 8);
    }
  }
}

// ---------------- fused fuse+head (2 waves/block, wave-private LDS) ----------------
__global__ __launch_bounds__(128) void fhead_k(
    const u16* __restrict__ hsht,
    const u16* __restrict__ hf2,
    const u16* __restrict__ W6, const u16* __restrict__ W7,
    const u16* __restrict__ W8, const u16* __restrict__ W9,
    const float* __restrict__ sc, const float* __restrict__ sh,
    void* __restrict__ dout, const int* __restrict__ flagp, int N)
{
  constexpr int LH = 72, LZ = 136;
  __shared__ u16 ldsH[2 * 16 * LH];
  __shared__ u16 ldsZ[2 * 16 * LZ];
  const int tid = threadIdx.x, w = tid >> 6, l = tid & 63;
  const int lrow = l & 15, lkb = (l >> 4) << 3;
  const int rowbase = blockIdx.x * 32 + w * 16;
  int r0 = rowbase + lrow; if (r0 >= N) r0 = N - 1;
  const int rl0 = (l >> 4) << 2;
  int gflag = *flagp;
  u16* lh = ldsH + w * 16 * LH;
  u16* lz = ldsZ + w * 16 * LZ;
  const size_t hoff = (size_t)N * 64;

  short8 pf[6];
#pragma unroll
  for (int k = 0; k < 6; k++)
    pf[k] = *(const short8*)(hf2 + (size_t)r0 * 192 + k * 32 + lkb);

  // ---- stage 1: h = relu(hsht @ W6 + b6) ----
  {
    floatx4 acc[4];
#pragma unroll
    for (int ct = 0; ct < 4; ct++) acc[ct] = (floatx4){0.f,0.f,0.f,0.f};
#pragma unroll
    for (int ks = 0; ks < 4; ks++) {
      short8 a = *(const short8*)(hsht + (size_t)r0 * 128 + ks * 32 + lkb);
#pragma unroll
      for (int ct = 0; ct < 4; ct++) {
        short8 b = *(const short8*)(W6 + ((size_t)(ks * 4 + ct) * 64 + l) * 8);
        acc[ct] = __builtin_amdgcn_mfma_f32_16x16x32_bf16(a, b, acc[ct], 0, 0, 0);
      }
    }
#pragma unroll
    for (int ct = 0; ct < 4; ct++) {
      int col = ct * 16 + lrow;
      float s = sc[512 + col], t = sh[512 + col];
#pragma unroll
      for (int r = 0; r < 4; r++) {
        int row = rowbase + rl0 + r;
        float v = fmaxf(acc[ct][r] * s + t, 0.f);
        lh[(rl0 + r) * LH + col] = f2b(v);
        if (gflag && row < N) ((float*)dout)[hoff + (size_t)row * 64 + col] = v;
      }
    }
  }
  __builtin_amdgcn_wave_barrier();

  if (!gflag) {
#pragma unroll
    for (int i = 0; i < 2; i++) {
      int c = i * 64 + l;
      int rl = c >> 3, o = c & 7;
      int row = rowbase + rl;
      if (row < N)
        *(short8*)((u16*)dout + hoff + (size_t)row * 64 + o * 8) = *(const short8*)(lh + rl * LH + o * 8);
    }
  }

  // ---- stage 2: z1 = relu(bn3([h | hf2] @ W7 + b7)) ----
  {
    floatx4 acc[8];
#pragma unroll
    for (int ct = 0; ct < 8; ct++) acc[ct] = (floatx4){0.f,0.f,0.f,0.f};
#pragma unroll
    for (int ks = 0; ks < 8; ks++) {
      short8 a;
      if (ks < 2) a = *(const short8*)(lh + lrow * LH + lkb + ks * 32);
      else        a = pf[ks - 2];
#pragma unroll
      for (int ct = 0; ct < 8; ct++) {
        short8 b = *(const short8*)(W7 + ((size_t)(ks * 8 + ct) * 64 + l) * 8);
        acc[ct] = __builtin_amdgcn_mfma_f32_16x16x32_bf16(a, b, acc[ct], 0, 0, 0);
      }
    }
#pragma unroll
    for (int ct = 0; ct < 8; ct++) {
      int col = ct * 16 + lrow;
      float s = sc[576 + col], t = sh[576 + col];
#pragma unroll
      for (int r = 0; r < 4; r++)
        lz[(rl0 + r) * LZ + col] = f2b(fmaxf(acc[ct][r] * s + t, 0.f));
    }
  }
  __builtin_amdgcn_wave_barrier();

  // ---- stage 3: z2 = relu(z1 @ W8 + b8) -> lh ----
  {
    floatx4 acc[4];
#pragma unroll
    for (int ct = 0; ct < 4; ct++) acc[ct] = (floatx4){0.f,0.f,0.f,0.f};
#pragma unroll
    for (int ks = 0; ks < 4; ks++) {
      short8 a = *(const short8*)(lz + lrow * LZ + lkb + ks * 32);
#pragma unroll
      for (int ct = 0; ct < 4; ct++) {
        short8 b = *(const short8*)(W8 + ((size_t)(ks * 4 + ct) * 64 + l) * 8);
        acc[ct] = __builtin_amdgcn_mfma_f32_16x16x32_bf16(a, b, acc[ct], 0, 0, 0);
      }
    }
#pragma unroll
    for (int ct = 0; ct < 4; ct++) {
      int col = ct * 16 + lrow;
      float s = sc[704 + col], t = sh[704 + col];
#pragma unroll
      for (int r = 0; r < 4; r++)
        lh[(rl0 + r) * LH + col] = f2b(fmaxf(acc[ct][r] * s + t, 0.f));
    }
  }
  __builtin_amdgcn_wave_barrier();

  // ---- stage 4: out = z2 @ W9 + b9 ----
  {
    floatx4 acc[4];
#pragma unroll
    for (int ct = 0; ct < 4; ct++) acc[ct] = (floatx4){0.f,0.f,0.f,0.f};
#pragma unroll
    for (int ks = 0; ks < 2; ks++) {
      short8 a = *(const short8*)(lh + lrow * LH + lkb + ks * 32);
#pragma unroll
      for (int ct = 0; ct < 4; ct++) {
        short8 b = *(const short8*)(W9 + ((size_t)(ks * 4 + ct) * 64 + l) * 8);
        acc[ct] = __builtin_amdgcn_mfma_f32_16x16x32_bf16(a, b, acc[ct], 0, 0, 0);
      }
    }
#pragma unroll
    for (int ct = 0; ct < 4; ct++) {
      int col = ct * 16 + lrow;
      float s = sc[768 + col], t = sh[768 + col];
#pragma unroll
      for (int r = 0; r < 4; r++) {
        int row = rowbase + rl0 + r;
        float v = acc[ct][r] * s + t;
        if (gflag) { if (row < N) ((float*)dout)[(size_t)row * 64 + col] = v; }
        else lz[(rl0 + r) * LZ + col] = f2b(v);
      }
    }
  }
  __builtin_amdgcn_wave_barrier();
  if (!gflag) {
#pragma unroll
    for (int i = 0; i < 2; i++) {
      int c = i * 64 + l;
      int rl = c >> 3, o = c & 7;
      int row = rowbase + rl;
      if (row < N)
        *(short8*)((u16*)dout + (size_t)row * 64 + o * 8) = *(const short8*)(lz + rl * LZ + o * 8);
    }
  }
}

// ---------------- chunked bucket histogram (256-node buckets, 512 bins) ----------------
#define CH 8192
__global__ __launch_bounds__(512) void histc_k(const int* __restrict__ dS, const int* __restrict__ dT,
                                               u32* __restrict__ hslS, u32* __restrict__ hslT, int E) {
  __shared__ u32 h[1024];
  int t = threadIdx.x;
  for (int i = t; i < 1024; i += 512) h[i] = 0;
  __syncthreads();
  int c0 = blockIdx.x * CH;
  int cend = c0 + CH; if (cend > E) cend = E;
  for (int i = c0 + t; i < cend; i += 512) {
    atomicAdd(&h[dS[i] >> 8], 1u);
    atomicAdd(&h[512 + (dT[i] >> 8)], 1u);
  }
  __syncthreads();
  int slice = blockIdx.x & 63;
  {
    u32 a = h[t], bt = h[512 + t];
    if (a)  atomicAdd(&hslS[t * 64 + slice], a);
    if (bt) atomicAdd(&hslT[t * 64 + slice], bt);
  }
}

// ---------------- scan chain (65536 elements, both graphs) ----------------
__global__ __launch_bounds__(256) void scan1_k(const u32* __restrict__ cnt, int* __restrict__ rowp,
                                               u32* __restrict__ bsum, int N) {
  __shared__ u32 sm[256];
  int t = threadIdx.x;
  int base = blockIdx.x * 1024 + t * 4;
  u32 v0 = 0, v1 = 0, v2 = 0, v3 = 0;
  if (base + 3 < N) {
    uint4 u = *(const uint4*)(cnt + base);
    v0 = u.x; v1 = u.y; v2 = u.z; v3 = u.w;
  } else {
    if (base + 0 < N) v0 = cnt[base + 0];
    if (base + 1 < N) v1 = cnt[base + 1];
    if (base + 2 < N) v2 = cnt[base + 2];
  }
  u32 tsum = v0 + v1 + v2 + v3;
  u32 x = tsum;
  sm[t] = x;
  for (int o = 1; o < 256; o <<= 1) {
    __syncthreads();
    u32 y = (t >= o) ? sm[t - o] : 0u;
    __syncthreads();
    x += y;
    sm[t] = x;
  }
  u32 ex = x - tsum;
  if (base + 0 < N) rowp[base + 0] = (int)ex;
  if (base + 1 < N) rowp[base + 1] = (int)(ex + v0);
  if (base + 2 < N) rowp[base + 2] = (int)(ex + v0 + v1);
  if (base + 3 < N) rowp[base + 3] = (int)(ex + v0 + v1 + v2);
  if (t == 255) bsum[blockIdx.x] = x;
}

__global__ __launch_bounds__(256) void scan2_k(u32* __restrict__ bsum, int nb, int* __restrict__ rowp, int N) {
  __shared__ u32 sm[256];
  int t = threadIdx.x;
  u32 v = (t < nb) ? bsum[t] : 0u;
  u32 x = v;
  sm[t] = x;
  for (int o = 1; o < 256; o <<= 1) {
    __syncthreads();
    u32 y = (t >= o) ? sm[t - o] : 0u;
    __syncthreads();
    x += y;
    sm[t] = x;
  }
  if (t < nb) bsum[t] = x - v;
  if (t == 255) rowp[N] = (int)x;
}

__global__ __launch_bounds__(256) void scan3_k(int* __restrict__ rowp, const u32* __restrict__ bsum, int N) {
  int t = threadIdx.x, base = blockIdx.x * 1024 + t * 4;
  u32 add = bsum[blockIdx.x];
#pragma unroll
  for (int j = 0; j < 4; j++) {
    int i = base + j;
    if (i < N) rowp[i] += (int)add;
  }
}

// ---------------- bucket bases ----------------
__global__ __launch_bounds__(256) void bbx_k(const int* __restrict__ oft, int* __restrict__ bb, int nbb) {
  int i = blockIdx.x * 256 + threadIdx.x;
  if (i <= nbb) bb[i] = oft[i * 64];
}

// ---------------- LDS-staged partition (512 bins, both graphs) ----------------
// pairs[i] = (dstLocal(8b) << 20) | src(<=20b)
__global__ __launch_bounds__(512) void part2_k(const int* __restrict__ spe, const int* __restrict__ tre,
                                               u32* __restrict__ cur0, u32* __restrict__ pairs,
                                               int E, int NC) {
  __shared__ u32 cntA[512];
  __shared__ u32 offA[512];
  __shared__ u32 sm[512];
  __shared__ u32 stage[CH];
  __shared__ u32 stot;
  int t = threadIdx.x;
  int gb = blockIdx.x;
  bool gT = gb >= NC;
  int cb = gT ? gb - NC : gb;
  const int* src = gT ? tre : spe;
  const int* dst = src + E;
  u32* cur = cur0 + (gT ? 32768 : 0);
  cntA[t] = 0;
  __syncthreads();
  int c0 = cb * CH;
  int cend = c0 + CH; if (cend > E) cend = E;
  for (int i = c0 + t; i < cend; i += 512)
    atomicAdd(&cntA[dst[i] >> 8], 1u);
  __syncthreads();
  u32 v = cntA[t], x = v;
  sm[t] = x;
  for (int o = 1; o < 512; o <<= 1) {
    __syncthreads();
    u32 y = (t >= o) ? sm[t - o] : 0u;
    __syncthreads();
    x += y;
    sm[t] = x;
  }
  u32 ex = x - v;
  __syncthreads();
  offA[t] = ex;
  cntA[t] = ex;     // cursor init
  if (t == 511) stot = x;
  __syncthreads();
  for (int i = c0 + t; i < cend; i += 512) {
    int d = dst[i];
    u32 pos = atomicAdd(&cntA[d >> 8], 1u);
    stage[pos] = ((u32)(d & 255) << 20) | (u32)src[i];
  }
  __syncthreads();
  int slice = cb & 63;
  {
    int bk = t;
    u32 beg = offA[bk];
    u32 fin = (bk == 511) ? stot : offA[bk + 1];
    u32 n = fin - beg;
    if (n) {
      u32 g = atomicAdd(&cur[(u32)bk * 64 + slice], n);
      for (u32 j = 0; j < n; j++) pairs[g + j] = stage[beg + j];
    }
  }
}

// ---------------- per-bucket degree -> dis (both graphs, 256-node buckets) ----------------
__global__ __launch_bounds__(256) void bdis_k(const u32* __restrict__ pairs, const int* __restrict__ bb,
                                              float* __restrict__ disS, float* __restrict__ disT,
                                              int nb, int N) {
  __shared__ u32 c[256];
  int b = blockIdx.x, t = threadIdx.x;
  bool gT = b >= nb;
  int j = gT ? b - nb : b;
  int bbi = (gT ? 512 : 0) + j;
  float* dis = gT ? disT : disS;
  c[t] = 0;
  __syncthreads();
  int base = bb[bbi], end = bb[bbi + 1];
  for (int i = base + t; i < end; i += 256)
    atomicAdd(&c[(pairs[i] >> 20) & 255], 1u);
  __syncthreads();
  int n = j * 256 + t;
  if (n < N) dis[n] = rsqrtf((float)c[t] + 1.f);
}

// ---------------- fused counting-sort + wide-gather SpMM (256-node buckets) ----------------
// eg = lane>>3 (edge slot), fo = (lane&7)*8 (feature octet). Parallel bin scan.
// 782 blocks <= 1024 resident slots (4/CU at 38KB LDS) -> single scheduling round.
#define SMX 8832
__device__ __forceinline__ void acc8(floatx2* a2, short8 v) {
  const u32* wv = (const u32*)&v;
#pragma unroll
  for (int p = 0; p < 4; p++) {
    u32 w = wv[p];
    floatx2 e;
    e.x = __uint_as_float(w << 16);
    e.y = __uint_as_float(w & 0xFFFF0000u);
    a2[p] += e;
  }
}

__global__ __launch_bounds__(512) void sortspmm_k(const u32* __restrict__ pairs, const int* __restrict__ bb,
                                                  const u16* __restrict__ hWdS, const u16* __restrict__ hWdT,
                                                  const float* __restrict__ biasS, const float* __restrict__ biasT,
                                                  u16* __restrict__ hsht, int nb, int N) {
  __shared__ u32 scnt[256];
  __shared__ u32 ssc[256];
  __shared__ u32 scur[256];
  __shared__ u32 stage[SMX];
  int b = blockIdx.x, t = threadIdx.x;
  bool gT = b >= nb;
  int j = gT ? b - nb : b;
  int bbi = (gT ? 512 : 0) + j;
  const u16* hWd = gT ? hWdT : hWdS;
  const float* biasf = gT ? biasT : biasS;
  int goff = gT ? 64 : 0;
  if (t < 256) scnt[t] = 0;
  __syncthreads();
  int base = bb[bbi], end = bb[bbi + 1];
  int size = end - base;
  if (size > SMX) size = SMX;
  for (int i = t; i < size; i += 512)
    atomicAdd(&scnt[(pairs[base + i] >> 20) & 255], 1u);
  __syncthreads();
  // parallel inclusive scan over 256 bins
  if (t < 256) ssc[t] = scnt[t];
  __syncthreads();
  for (int o = 1; o < 256; o <<= 1) {
    u32 y = 0;
    if (t < 256 && t >= o) y = ssc[t - o];
    __syncthreads();
    if (t < 256) ssc[t] += y;
    __syncthreads();
  }
  if (t < 256) scur[t] = ssc[t] - scnt[t];
  __syncthreads();
  for (int i = t; i < size; i += 512) {
    u32 p = pairs[base + i];
    u32 nl = (p >> 20) & 255;
    u32 pos = atomicAdd(&scur[nl], 1u);
    stage[pos] = p & 0xFFFFFu;
  }
  __syncthreads();

  const int wid = t >> 6, lane = t & 63;
  const int eg = lane >> 3;
  const int fo = (lane & 7) * 8;
  const u16* hp = hWd + fo;
  floatx2 bi2[4];
#pragma unroll
  for (int p = 0; p < 4; p++) bi2[p] = *(const floatx2*)(biasf + fo + 2 * p);

#pragma unroll 1
  for (int k = 0; k < 32; k++) {
    int nl = wid + (k << 3);
    int n = j * 256 + nl;
    if (n >= N) continue;
    int cnt = (int)scnt[nl];
    int off = (int)(ssc[nl] - scnt[nl]);
    floatx2 a2[4];
#pragma unroll
    for (int p = 0; p < 4; p++) a2[p] = (floatx2){0.f, 0.f};
    int i = 0;
    for (; i + 16 <= cnt; i += 16) {
      u32 s0 = stage[off + i + eg];
      u32 s1 = stage[off + i + 8 + eg];
      short8 v0 = *(const short8*)(hp + (size_t)s0 * 64);
      short8 v1 = *(const short8*)(hp + (size_t)s1 * 64);
      acc8(a2, v0);
      acc8(a2, v1);
    }
    if (i + 8 <= cnt) {
      u32 s0 = stage[off + i + eg];
      acc8(a2, *(const short8*)(hp + (size_t)s0 * 64));
      i += 8;
    }
    int rem = cnt - i;
    if (eg < rem) {
      u32 s0 = stage[off + i + eg];
      acc8(a2, *(const short8*)(hp + (size_t)s0 * 64));
    }
#pragma unroll
    for (int m = 8; m <= 32; m <<= 1) {
#pragma unroll
      for (int p = 0; p < 4; p++) {
        floatx2 o;
        o.x = __shfl_xor(a2[p].x, m, 64);
        o.y = __shfl_xor(a2[p].y, m, 64);
        a2[p] += o;
      }
    }
    float disn = rsqrtf((float)cnt + 1.f);
    short8 sv = *(const short8*)(hp + (size_t)n * 64);
    const u32* swv = (const u32*)&sv;
    short8 o;
    u32* ow = (u32*)&o;
#pragma unroll
    for (int p = 0; p < 4; p++) {
      u32 w = swv[p];
      float lo = disn * (a2[p].x + __uint_as_float(w << 16)) + bi2[p].x;
      float hi = disn * (a2[p].y + __uint_as_float(w & 0xFFFF0000u)) + bi2[p].y;
      lo = fmaxf(lo, 0.f);
      hi = fmaxf(hi, 0.f);
      ow[p] = ((u32)f2b(hi) << 16) | (u32)f2b(lo);
    }
    if (eg == 0)
      *(short8*)(hsht + (size_t)n * 128 + goff + fo) = o;
  }
}

extern "C" void kernel_launch(void* const* d_in, const int* in_sizes, int n_in,
                              void* d_out, int out_size, void* d_ws, size_t ws_size,
                              hipStream_t stream) {
  const int N = in_sizes[0] / 256;
  const int E = in_sizes[2] / 2;
  const int nb = (N + 255) >> 8;         // 256-node buckets
  const int NC = (E + CH - 1) / CH;
  const void* ctx = d_in[0];
  const void* vis = d_in[1];
  const int* spe = (const int*)d_in[2];
  const int* tre = (const int*)d_in[3];
  (void)n_in; (void)out_size; (void)ws_size;

  char* ws = (char*)d_ws;
  size_t off = 0;
  auto alloc = [&](size_t b) { size_t r = off; off += (b + 255) & ~(size_t)255; return r; };
  const size_t o_hsl  = alloc(65536 * 4);              // 2 graphs x 512 buckets x 64 slices
  const size_t o_oft  = alloc(65544 * 4);
  const size_t o_bb   = alloc(1032 * 4);
  const size_t o_bsum = alloc(256 * 4);
  const size_t o_disS = alloc((size_t)N * 4);
  const size_t o_disT = alloc((size_t)N * 4);
  const size_t o_pr   = alloc((size_t)2 * E * 4);
  const size_t o_hf2  = alloc((size_t)N * 192 * 2);
  const size_t o_hsht = alloc((size_t)N * 128 * 2);
  const size_t o_hWdS = alloc((size_t)N * 64 * 2);
  const size_t o_hWdT = alloc((size_t)N * 64 * 2);
  const size_t o_wf   = alloc((size_t)135168 * 2);
  const size_t o_sc   = alloc((size_t)896 * 4);
  const size_t o_sh   = alloc((size_t)896 * 4);
  const size_t o_fl   = alloc(256);

  u32* hsl  = (u32*)(ws + o_hsl);
  int* oft  = (int*)(ws + o_oft);
  int* bb   = (int*)(ws + o_bb);
  u32* bsum = (u32*)(ws + o_bsum);
  float* disS = (float*)(ws + o_disS);
  float* disT = (float*)(ws + o_disT);
  u32* pairs = (u32*)(ws + o_pr);
  u16* hf2   = (u16*)(ws + o_hf2);
  u16* hsht  = (u16*)(ws + o_hsht);
  u16* hWdS  = (u16*)(ws + o_hWdS);
  u16* hWdT  = (u16*)(ws + o_hWdT);
  u16* wf    = (u16*)(ws + o_wf);
  float* sc  = (float*)(ws + o_sc);
  float* sh  = (float*)(ws + o_sh);
  int* flagp = (int*)(ws + o_fl);

  det_k<<<1, 256, 0, stream>>>((const u16*)ctx, 4096, flagp);
  hipMemsetAsync(ws + o_hsl, 0, 65536 * 4, stream);

  // ---- weight frag prep ----
  const int wfoff[10] = {0, 32768, 49152, 53248, 57344, 69632, 81920, 90112, 122880, 131072};
  const int wbase[10] = {0, 4096, 6144, 6656, 7168, 8704, 10240, 11264, 15360, 16384};
  const int wM[10]    = {128, 128, 64, 64, 64, 64, 64, 128, 64, 64};
  const int widx[10]  = {4, 10, 16, 18, 20, 22, 24, 26, 32, 34};
  WPack wp;
  for (int i = 0; i < 10; i++) wp.e[i] = {d_in[widx[i]], wf + (size_t)wfoff[i], wM[i], wbase[i]};
  wp.total = 16896;
  wprep_k<<<(wp.total + 255) / 256, 256, 0, stream>>>(wp, flagp);

  // ---- scale/shift prep ----
  const int sbase[11] = {0, 128, 256, 320, 384, 448, 512, 576, 704, 768, 832};
  const int bidx[11] = {5, 11, 17, 19, 21, 23, 25, 27, 33, 35, -1};
  const int gidx[11] = {6, 12, -1, -1, -1, -1, -1, 28, -1, -1, -1};
  SPack spk;
  for (int i = 0; i < 11; i++) {
    const void* bias = bidx[i] >= 0 ? d_in[bidx[i]] : nullptr;
    const void* g = gidx[i] >= 0 ? d_in[gidx[i]] : nullptr;
    const void* b = gidx[i] >= 0 ? d_in[gidx[i] + 1] : nullptr;
    const void* m = gidx[i] >= 0 ? d_in[gidx[i] + 2] : nullptr;
    const void* v = gidx[i] >= 0 ? d_in[gidx[i] + 3] : nullptr;
    spk.e[i] = {bias, g, b, m, v, sbase[i]};
  }
  spk.sc = sc; spk.sh = sh; spk.total = 896;
  sprep_k<<<4, 256, 0, stream>>>(spk, flagp);

  // ---- graph prep ----
  histc_k<<<NC, 512, 0, stream>>>(spe + E, tre + E, hsl, hsl + 32768, E);
  scan1_k<<<64, 256, 0, stream>>>(hsl, oft, bsum, 65536);
  scan2_k<<<1, 256, 0, stream>>>(bsum, 64, oft, 65536);
  scan3_k<<<64, 256, 0, stream>>>(oft, bsum, 65536);
  bbx_k<<<5, 256, 0, stream>>>(oft, bb, 1024);
  part2_k<<<2 * NC, 512, 0, stream>>>(spe, tre, (u32*)oft, pairs, E, NC);
  bdis_k<<<2 * nb, 256, 0, stream>>>(pairs, bb, disS, disT, nb, N);

  const int G64 = (N + 63) / 64;
  const int G32 = (N + 31) / 32;
  tow_k<<<G64, 256, 0, stream>>>(ctx, vis,
      wf + wfoff[0], wf + wfoff[1], wf + wfoff[2], wf + wfoff[3],
      wf + wfoff[4], wf + wfoff[5],
      sc, sh, disS, disT, hf2, hWdS, hWdT, flagp, N);
  sortspmm_k<<<2 * nb, 512, 0, stream>>>(pairs, bb, hWdS, hWdT, sh + 384, sh + 448, hsht, nb, N);
  fhead_k<<<G32, 128, 0, stream>>>(hsht, hf2,
      wf + wfoff[6], wf + wfoff[7], wf + wfoff[8], wf + wfoff[9],
      sc, sh, d_out, flagp, N);
}